// Round 1
// baseline (291.378 us; speedup 1.0000x reference)
//
#include <hip/hip_runtime.h>
#include <cstdint>
#include <cstddef>

#define DEVI __device__ __forceinline__

typedef short    shortx8 __attribute__((ext_vector_type(8)));
typedef __bf16   bf16x8  __attribute__((ext_vector_type(8)));
typedef float    floatx4 __attribute__((ext_vector_type(4)));

// ---- scalar bf16 conversion helpers (RN-even), buffers held as ushort ----
DEVI unsigned short f2b(float f) {
    union { float f; unsigned u; } a; a.f = f;
    unsigned r = a.u + 0x7fffu + ((a.u >> 16) & 1u);
    return (unsigned short)(r >> 16);
}
DEVI float b2f(unsigned short u) {
    union { unsigned u; float f; } a; a.u = ((unsigned)u) << 16;
    return a.f;
}

DEVI floatx4 mfma_bf16(bf16x8 a, bf16x8 b, floatx4 c) {
    return __builtin_amdgcn_mfma_f32_16x16x32_bf16(a, b, c, 0, 0, 0);
}

DEVI void glds16(const ushort* g, ushort* l) {
    __builtin_amdgcn_global_load_lds(
        (const __attribute__((address_space(1))) void*)g,
        (__attribute__((address_space(3))) void*)l, 16, 0, 0);
}

// ---------------- conversions / packing ----------------
__global__ void k_cvt(const float* __restrict__ x, ushort* __restrict__ xb) {
    size_t i = ((size_t)blockIdx.x * 256 + threadIdx.x) * 8;
    float4 v0 = *(const float4*)(x + i);
    float4 v1 = *(const float4*)(x + i + 4);
    shortx8 o;
    o[0] = (short)f2b(v0.x); o[1] = (short)f2b(v0.y);
    o[2] = (short)f2b(v0.z); o[3] = (short)f2b(v0.w);
    o[4] = (short)f2b(v1.x); o[5] = (short)f2b(v1.y);
    o[6] = (short)f2b(v1.z); o[7] = (short)f2b(v1.w);
    *(shortx8*)(xb + i) = o;
}

// transpose W [768 in][768 out] fp32 -> Wt [out][in] bf16 (64x64 tiles)
__global__ void k_packw(const float* __restrict__ Wq, const float* __restrict__ Wk,
                        const float* __restrict__ Wv, const float* __restrict__ Wo,
                        ushort* __restrict__ Wt, ushort* __restrict__ Wot) {
    const int zi = blockIdx.z;
    const float* W = (zi == 0) ? Wq : (zi == 1) ? Wk : (zi == 2) ? Wv : Wo;
    __shared__ float tile[64][65];
    const int i0 = blockIdx.x * 64, j0 = blockIdx.y * 64;
    const int t = threadIdx.x;
    const int c = t & 63, r4 = t >> 6;
    for (int rr = r4; rr < 64; rr += 4)
        tile[rr][c] = W[(size_t)(i0 + rr) * 768 + j0 + c];
    __syncthreads();
    ushort* dst = (zi < 3) ? (Wt + (size_t)(zi * 768) * 768) : Wot;
    for (int jj = r4; jj < 64; jj += 4)
        dst[(size_t)(j0 + jj) * 768 + i0 + c] = f2b(tile[c][jj]);
}

__global__ void k_bias(const float* __restrict__ bq, const float* __restrict__ bk,
                       const float* __restrict__ bv, float* __restrict__ bqkv) {
    int j = blockIdx.x * 256 + threadIdx.x;
    if (j >= 2304) return;
    const float* src = (j < 768) ? bq : (j < 1536) ? bk : bv;
    bqkv[j] = src[j % 768];
}

// ---------------- main GEMM (m97 structure) ----------------
// A [16384 x 768] bf16 row-major, Bt [N x 768] bf16 row-major (B transposed).
// MODE 0: QKV epilogue: +bias, phi on cols<1536, bf16 store. MODE 1: +bias, fp32 store.
template <int MODE>
__global__ __launch_bounds__(256, 2) void k_gemm(
    const ushort* __restrict__ A, const ushort* __restrict__ Bt,
    const float* __restrict__ bias, void* __restrict__ Cout, int Ncols) {
    constexpr int K = 768;
    __shared__ ushort As[128 * 32];
    __shared__ ushort Bs[128 * 32];
    const int m0 = blockIdx.x * 128;
    const int n0 = blockIdx.y * 128;
    const int tid = threadIdx.x;
    const int w = tid >> 6, lane = tid & 63;

    const int srow = lane >> 2;            // staging: lane -> row within 16-row slab
    const int scol = (lane & 3) * 8;       // 8 bf16 = 16B per lane
    const ushort* ag0 = A  + (size_t)(m0 + w * 32 +      srow) * K + scol;
    const ushort* ag1 = A  + (size_t)(m0 + w * 32 + 16 + srow) * K + scol;
    const ushort* bg0 = Bt + (size_t)(n0 + w * 32 +      srow) * K + scol;
    const ushort* bg1 = Bt + (size_t)(n0 + w * 32 + 16 + srow) * K + scol;
    ushort* al0 = As + (w * 32     ) * 32;   // wave-uniform LDS bases
    ushort* al1 = As + (w * 32 + 16) * 32;
    ushort* bl0 = Bs + (w * 32     ) * 32;
    ushort* bl1 = Bs + (w * 32 + 16) * 32;

    const int rBase = (w >> 1) * 64;
    const int nBase = (w & 1) * 64;
    const int fr = lane & 15;
    const int fk = (lane >> 4) * 8;

    floatx4 acc[4][4] = {};

    for (int k0 = 0; k0 < K; k0 += 32) {
        glds16(ag0 + k0, al0);
        glds16(ag1 + k0, al1);
        glds16(bg0 + k0, bl0);
        glds16(bg1 + k0, bl1);
        __syncthreads();   // vmcnt(0) drain makes staged LDS visible
        bf16x8 af[4], bf[4];
#pragma unroll
        for (int rt = 0; rt < 4; ++rt)
            af[rt] = *(const bf16x8*)(As + (rBase + rt * 16 + fr) * 32 + fk);
#pragma unroll
        for (int nt = 0; nt < 4; ++nt)
            bf[nt] = *(const bf16x8*)(Bs + (nBase + nt * 16 + fr) * 32 + fk);
#pragma unroll
        for (int rt = 0; rt < 4; ++rt)
#pragma unroll
            for (int nt = 0; nt < 4; ++nt)
                acc[rt][nt] = mfma_bf16(af[rt], bf[nt], acc[rt][nt]);
        __syncthreads();   // protect LDS against next iteration's staging
    }

#pragma unroll
    for (int rt = 0; rt < 4; ++rt) {
#pragma unroll
        for (int nt = 0; nt < 4; ++nt) {
#pragma unroll
            for (int r = 0; r < 4; ++r) {
                int m = m0 + rBase + rt * 16 + (lane >> 4) * 4 + r;
                int n = n0 + nBase + nt * 16 + fr;
                float v = acc[rt][nt][r] + bias[n];
                if (MODE == 0) {
                    if (n < 1536) v = (v > 0.f) ? (v + 1.f) : __expf(v);  // phi = elu+1
                    ((ushort*)Cout)[(size_t)m * Ncols + n] = f2b(v);
                } else {
                    ((float*)Cout)[(size_t)m * Ncols + n] = v;
                }
            }
        }
    }
}

// ---------------- kv / ksum partials (VALU) ----------------
// grid (48 bh, 16 n-splits of 256). kvp layout: [48][16][68][64] fp32
// rows 0..63 = kv[d][e] partial, rows 64..67 = ksum partial per dg-group.
__global__ __launch_bounds__(256) void k_kv(const ushort* __restrict__ QKV,
                                            float* __restrict__ kvp) {
    const int bh = blockIdx.x, s = blockIdx.y;
    const int bb = bh / 12, head = bh % 12;
    __shared__ float ksh[32][68];
    __shared__ float vsh[32][68];
    const int t = threadIdx.x;
    const int e = t & 63, dg = t >> 6;
    const int nl = t >> 3, c8 = (t & 7) * 8;
    float acc[16] = {};
    float aks = 0.f;
    const ushort* kb = QKV + (size_t)(bb * 4096 + s * 256) * 2304 + 768 + head * 64 + c8;
    for (int it = 0; it < 8; ++it) {
        __syncthreads();
        const ushort* kp = kb + (size_t)(it * 32 + nl) * 2304;
        shortx8 kr = *(const shortx8*)kp;
        shortx8 vr = *(const shortx8*)(kp + 768);
#pragma unroll
        for (int i = 0; i < 8; ++i) {
            ksh[nl][c8 + i] = b2f((unsigned short)kr[i]);
            vsh[nl][c8 + i] = b2f((unsigned short)vr[i]);
        }
        __syncthreads();
#pragma unroll 4
        for (int j = 0; j < 32; ++j) {
            float vv = vsh[j][e];                         // lane-consecutive, conflict-free
            const float* krow = &ksh[j][dg * 16];         // wave-uniform -> broadcast
            floatx4 ka = *(const floatx4*)(krow);
            floatx4 kb2 = *(const floatx4*)(krow + 4);
            floatx4 kc = *(const floatx4*)(krow + 8);
            floatx4 kd = *(const floatx4*)(krow + 12);
#pragma unroll
            for (int q = 0; q < 4; ++q) {
                acc[q]      += ka[q] * vv;
                acc[4 + q]  += kb2[q] * vv;
                acc[8 + q]  += kc[q] * vv;
                acc[12 + q] += kd[q] * vv;
            }
        }
#pragma unroll
        for (int j4 = 0; j4 < 8; ++j4) aks += ksh[j4 * 4 + dg][e];
    }
    float* dst = kvp + (size_t)(bh * 16 + s) * (68 * 64);
#pragma unroll
    for (int q = 0; q < 16; ++q) dst[(dg * 16 + q) * 64 + e] = acc[q];
    dst[(64 + dg) * 64 + e] = aks;
}

// reduce partials -> kvr [48][65][64]  (row 64 = ksum[d])
__global__ void k_kvred(const float* __restrict__ kvp, float* __restrict__ kvr) {
    int idx = blockIdx.x * 256 + threadIdx.x;
    if (idx >= 48 * 65 * 64) return;
    int bh = idx / 4160;
    int rem = idx % 4160;
    int r = rem >> 6, c = rem & 63;
    const float* p = kvp + (size_t)bh * 16 * 4352;
    float sum = 0.f;
    if (r < 64) {
        for (int s = 0; s < 16; ++s) sum += p[s * 4352 + r * 64 + c];
    } else {
        for (int s = 0; s < 16; ++s)
#pragma unroll
            for (int x = 0; x < 4; ++x) sum += p[s * 4352 + (64 + x) * 64 + c];
    }
    kvr[idx] = sum;
}

// ---------------- num + z + normed (MFMA) ----------------
// grid (48 bh, 32 l-chunks of 128). C = Q[128x64] @ [kv | ksum](64 x 80),
// column 64 of C is the denominator. normed stored bf16 [16384][768].
__global__ __launch_bounds__(256) void k_num(const ushort* __restrict__ QKV,
                                             const float* __restrict__ kvr,
                                             ushort* __restrict__ normed) {
    const int bh = blockIdx.x, l0 = blockIdx.y * 128;
    const int bb = bh / 12, head = bh % 12;
    __shared__ ushort qsh[128 * 72];  // padded stride 72 to break bank conflicts
    __shared__ ushort kvT[80 * 72];   // kvT[e][d] = kv[d][e]; row 64 = ksum[d]
    __shared__ float dnm[128];
    const int t = threadIdx.x, w = t >> 6, lane = t & 63;

    const float* kvb = kvr + (size_t)bh * 4160;
    for (int idx = t; idx < 4160; idx += 256) {
        int r = idx >> 6, c = idx & 63;
        unsigned short v = f2b(kvb[idx]);
        if (r < 64) kvT[c * 72 + r] = v;
        else        kvT[64 * 72 + c] = v;
    }
    for (int idx = t; idx < 15 * 72; idx += 256) kvT[65 * 72 + idx] = 0;  // junk rows 65..79

    const ushort* qg = QKV + (size_t)(bb * 4096 + l0) * 2304 + head * 64;
    {
        int row = t >> 3, c8 = (t & 7) * 8;
#pragma unroll
        for (int i = 0; i < 4; ++i) {
            shortx8 v = *(const shortx8*)(qg + (size_t)(i * 32 + row) * 2304 + c8);
            *(shortx8*)(qsh + (i * 32 + row) * 72 + c8) = v;
        }
    }
    __syncthreads();

    const int fr = lane & 15, fk = (lane >> 4) * 8;
    floatx4 acc[2][5] = {};
#pragma unroll
    for (int kc = 0; kc < 2; ++kc) {
        bf16x8 a[2], b[5];
#pragma unroll
        for (int rt = 0; rt < 2; ++rt)
            a[rt] = *(const bf16x8*)(qsh + (w * 32 + rt * 16 + fr) * 72 + kc * 32 + fk);
#pragma unroll
        for (int nt = 0; nt < 5; ++nt)
            b[nt] = *(const bf16x8*)(kvT + (nt * 16 + fr) * 72 + kc * 32 + fk);
#pragma unroll
        for (int rt = 0; rt < 2; ++rt)
#pragma unroll
            for (int nt = 0; nt < 5; ++nt)
                acc[rt][nt] = mfma_bf16(a[rt], b[nt], acc[rt][nt]);
    }
    if (fr == 0) {  // C col 64 = q . ksum
#pragma unroll
        for (int rt = 0; rt < 2; ++rt)
#pragma unroll
            for (int r = 0; r < 4; ++r)
                dnm[w * 32 + rt * 16 + (lane >> 4) * 4 + r] = acc[rt][4][r];
    }
    __syncthreads();
#pragma unroll
    for (int rt = 0; rt < 2; ++rt) {
#pragma unroll
        for (int r = 0; r < 4; ++r) {
            int ml = w * 32 + rt * 16 + (lane >> 4) * 4 + r;
            float z = 1.f / dnm[ml];
            size_t base = (size_t)(bb * 4096 + l0 + ml) * 768 + head * 64;
#pragma unroll
            for (int nt = 0; nt < 4; ++nt)
                normed[base + nt * 16 + fr] = f2b(acc[rt][nt][r] * z);
        }
    }
}

// ---------------- launch ----------------
extern "C" void kernel_launch(void* const* d_in, const int* in_sizes, int n_in,
                              void* d_out, int out_size, void* d_ws, size_t ws_size,
                              hipStream_t stream) {
    const float* x  = (const float*)d_in[0];
    const float* Wq = (const float*)d_in[1];
    const float* bq = (const float*)d_in[2];
    const float* Wk = (const float*)d_in[3];
    const float* bk = (const float*)d_in[4];
    const float* Wv = (const float*)d_in[5];
    const float* bv = (const float*)d_in[6];
    const float* Wo = (const float*)d_in[7];
    const float* bo = (const float*)d_in[8];

    char* ws = (char*)d_ws;
    ushort* Xb   = (ushort*)(ws);                 // 25,165,824 B (reused as `normed` later)
    ushort* Wt   = (ushort*)(ws + 25165824);      //  3,538,944 B  [2304][768] bf16
    ushort* Wot  = (ushort*)(ws + 28704768);      //  1,179,648 B  [768][768] bf16
    float*  bqkv = (float*)(ws + 29884416);       //      9,216 B
    ushort* QKV  = (ushort*)(ws + 29893632);      // 75,497,472 B  [16384][2304] bf16
    float*  kvp  = (float*)(ws + 105391104);      // 13,369,344 B  [48][16][68][64] fp32
    float*  kvr  = (float*)(ws + 118760448);      //    798,720 B  [48][65][64] fp32
    ushort* normed = Xb;                          // Xb dead after QKV GEMM

    k_cvt  <<<dim3(6144),        256, 0, stream>>>(x, Xb);
    k_packw<<<dim3(12, 12, 4),   256, 0, stream>>>(Wq, Wk, Wv, Wo, Wt, Wot);
    k_bias <<<dim3(9),           256, 0, stream>>>(bq, bk, bv, bqkv);
    k_gemm<0><<<dim3(128, 18),   256, 0, stream>>>(Xb, Wt, bqkv, (void*)QKV, 2304);
    k_kv   <<<dim3(48, 16),      256, 0, stream>>>(QKV, kvp);
    k_kvred<<<dim3(780),         256, 0, stream>>>(kvp, kvr);
    k_num  <<<dim3(48, 32),      256, 0, stream>>>(QKV, kvr, normed);
    k_gemm<1><<<dim3(128, 6),    256, 0, stream>>>(normed, Wot, bo, d_out, 768);
}

// Round 2
// 250.628 us; speedup vs baseline: 1.1626x; 1.1626x over previous
//
#include <hip/hip_runtime.h>
#include <cstdint>
#include <cstddef>

#define DEVI __device__ __forceinline__

typedef short    shortx8 __attribute__((ext_vector_type(8)));
typedef short    shortx4 __attribute__((ext_vector_type(4)));
typedef __bf16   bf16x8  __attribute__((ext_vector_type(8)));
typedef float    floatx4 __attribute__((ext_vector_type(4)));

// ---- scalar bf16 conversion helpers (RN-even), buffers held as ushort ----
DEVI unsigned short f2b(float f) {
    union { float f; unsigned u; } a; a.f = f;
    unsigned r = a.u + 0x7fffu + ((a.u >> 16) & 1u);
    return (unsigned short)(r >> 16);
}
DEVI float b2f(unsigned short u) {
    union { unsigned u; float f; } a; a.u = ((unsigned)u) << 16;
    return a.f;
}

DEVI floatx4 mfma_bf16(bf16x8 a, bf16x8 b, floatx4 c) {
    return __builtin_amdgcn_mfma_f32_16x16x32_bf16(a, b, c, 0, 0, 0);
}

DEVI void glds16(const ushort* g, ushort* l) {
    __builtin_amdgcn_global_load_lds(
        (const __attribute__((address_space(1))) void*)g,
        (__attribute__((address_space(3))) void*)l, 16, 0, 0);
}

// ---------------- conversions / packing ----------------
__global__ void k_cvt(const float* __restrict__ x, ushort* __restrict__ xb) {
    size_t i = ((size_t)blockIdx.x * 256 + threadIdx.x) * 8;
    float4 v0 = *(const float4*)(x + i);
    float4 v1 = *(const float4*)(x + i + 4);
    shortx8 o;
    o[0] = (short)f2b(v0.x); o[1] = (short)f2b(v0.y);
    o[2] = (short)f2b(v0.z); o[3] = (short)f2b(v0.w);
    o[4] = (short)f2b(v1.x); o[5] = (short)f2b(v1.y);
    o[6] = (short)f2b(v1.z); o[7] = (short)f2b(v1.w);
    *(shortx8*)(xb + i) = o;
}

// transpose W [768 in][768 out] fp32 -> Wt [out][in] bf16 (64x64 tiles)
__global__ void k_packw(const float* __restrict__ Wq, const float* __restrict__ Wk,
                        const float* __restrict__ Wv, const float* __restrict__ Wo,
                        ushort* __restrict__ Wt, ushort* __restrict__ Wot) {
    const int zi = blockIdx.z;
    const float* W = (zi == 0) ? Wq : (zi == 1) ? Wk : (zi == 2) ? Wv : Wo;
    __shared__ float tile[64][65];
    const int i0 = blockIdx.x * 64, j0 = blockIdx.y * 64;
    const int t = threadIdx.x;
    const int c = t & 63, r4 = t >> 6;
    for (int rr = r4; rr < 64; rr += 4)
        tile[rr][c] = W[(size_t)(i0 + rr) * 768 + j0 + c];
    __syncthreads();
    ushort* dst = (zi < 3) ? (Wt + (size_t)(zi * 768) * 768) : Wot;
    for (int jj = r4; jj < 64; jj += 4)
        dst[(size_t)(j0 + jj) * 768 + i0 + c] = f2b(tile[c][jj]);
}

__global__ void k_bias(const float* __restrict__ bq, const float* __restrict__ bk,
                       const float* __restrict__ bv, float* __restrict__ bqkv) {
    int j = blockIdx.x * 256 + threadIdx.x;
    if (j >= 2304) return;
    const float* src = (j < 768) ? bq : (j < 1536) ? bk : bv;
    bqkv[j] = src[j % 768];
}

// ---------------- main GEMM (m97 structure + XOR bank swizzle) ----------------
// LDS slot (l&3) of row r holds global k-chunk (l&3)^((r&15)>>1&3); staging
// permutes the SOURCE column per lane (coalescing preserved, glds16 stays flat),
// fragment reads XOR their k-chunk likewise -> 2-way max bank aliasing (free).
template <int MODE>
__global__ __launch_bounds__(256, 2) void k_gemm(
    const ushort* __restrict__ A, const ushort* __restrict__ Bt,
    const float* __restrict__ bias, void* __restrict__ Cout, int Ncols) {
    constexpr int K = 768;
    __shared__ ushort As[128 * 32];
    __shared__ ushort Bs[128 * 32];
    const int m0 = blockIdx.x * 128;
    const int n0 = blockIdx.y * 128;
    const int tid = threadIdx.x;
    const int w = tid >> 6, lane = tid & 63;

    const int srow = lane >> 2;                              // staging row in 16-slab
    const int scol = ((lane & 3) ^ ((srow >> 1) & 3)) * 8;   // swizzled source chunk
    const ushort* ag0 = A  + (size_t)(m0 + w * 32 +      srow) * K + scol;
    const ushort* ag1 = A  + (size_t)(m0 + w * 32 + 16 + srow) * K + scol;
    const ushort* bg0 = Bt + (size_t)(n0 + w * 32 +      srow) * K + scol;
    const ushort* bg1 = Bt + (size_t)(n0 + w * 32 + 16 + srow) * K + scol;
    ushort* al0 = As + (w * 32     ) * 32;   // wave-uniform LDS bases (flat)
    ushort* al1 = As + (w * 32 + 16) * 32;
    ushort* bl0 = Bs + (w * 32     ) * 32;
    ushort* bl1 = Bs + (w * 32 + 16) * 32;

    const int rBase = (w >> 1) * 64;
    const int nBase = (w & 1) * 64;
    const int fr = lane & 15;
    const int fks = (((lane >> 4) ^ ((fr >> 1) & 3))) * 8;   // swizzled frag chunk

    floatx4 acc[4][4] = {};

    for (int k0 = 0; k0 < K; k0 += 32) {
        glds16(ag0 + k0, al0);
        glds16(ag1 + k0, al1);
        glds16(bg0 + k0, bl0);
        glds16(bg1 + k0, bl1);
        __syncthreads();
        bf16x8 af[4], bf[4];
#pragma unroll
        for (int rt = 0; rt < 4; ++rt)
            af[rt] = *(const bf16x8*)(As + (rBase + rt * 16 + fr) * 32 + fks);
#pragma unroll
        for (int nt = 0; nt < 4; ++nt)
            bf[nt] = *(const bf16x8*)(Bs + (nBase + nt * 16 + fr) * 32 + fks);
#pragma unroll
        for (int rt = 0; rt < 4; ++rt)
#pragma unroll
            for (int nt = 0; nt < 4; ++nt)
                acc[rt][nt] = mfma_bf16(af[rt], bf[nt], acc[rt][nt]);
        __syncthreads();
    }

#pragma unroll
    for (int rt = 0; rt < 4; ++rt) {
#pragma unroll
        for (int nt = 0; nt < 4; ++nt) {
#pragma unroll
            for (int r = 0; r < 4; ++r) {
                int m = m0 + rBase + rt * 16 + (lane >> 4) * 4 + r;
                int n = n0 + nBase + nt * 16 + fr;
                float v = acc[rt][nt][r] + bias[n];
                if (MODE == 0) {
                    if (n < 1536) v = (v > 0.f) ? (v + 1.f) : __expf(v);  // phi
                    ((ushort*)Cout)[(size_t)m * Ncols + n] = f2b(v);
                } else {
                    ((float*)Cout)[(size_t)m * Ncols + n] = v;
                }
            }
        }
    }
}

// ---------------- kv + ksum via MFMA ----------------
// Per (bh, split): C[m][d] = sum_n A[m][n] * k[n][d], with A rows 0..63 = v^T
// (A[e][n] = v[n][e]) and A row 64 = ones -> C rows 0..63 = kv[d][e] in [e][d]
// layout, C row 64 = ksum[d]. Exactly the layout k_num consumes.
// grid (48, 8); block 256 (4 waves; wave w owns d-range [w*16, w*16+16)).
__global__ __launch_bounds__(256) void k_kv(const ushort* __restrict__ QKV,
                                            float* __restrict__ kvp) {
    const int bh = blockIdx.x, s = blockIdx.y;
    const int bb = bh / 12, head = bh % 12;
    __shared__ ushort kS[64 * 68];   // [n][d] stride 68 (2-way max on transposed reads)
    __shared__ ushort vS[64 * 68];
    const int t = threadIdx.x, w = t >> 6, lane = t & 63;
    const int fr = lane & 15, fk = (lane >> 4) * 8;

    floatx4 acc[5] = {};
    const int n_ld = t >> 2, c16 = (t & 3) * 16;
    const ushort* base = QKV + (size_t)(bb * 4096 + s * 512) * 2304 + 768 + head * 64 + c16;

    for (int rr = 0; rr < 8; ++rr) {
        if (rr) __syncthreads();
        {   // stage 64 rows of k,v, layout [n][d]
            const ushort* kp = base + (size_t)(rr * 64 + n_ld) * 2304;
            union { shortx8 v8; shortx4 v4[2]; } k0, k1, v0, v1;
            k0.v8 = *(const shortx8*)(kp);
            k1.v8 = *(const shortx8*)(kp + 8);
            v0.v8 = *(const shortx8*)(kp + 768);
            v1.v8 = *(const shortx8*)(kp + 776);
            ushort* kd = kS + n_ld * 68 + c16;
            ushort* vd = vS + n_ld * 68 + c16;
            *(shortx4*)(kd)     = k0.v4[0]; *(shortx4*)(kd + 4)  = k0.v4[1];
            *(shortx4*)(kd + 8) = k1.v4[0]; *(shortx4*)(kd + 12) = k1.v4[1];
            *(shortx4*)(vd)     = v0.v4[0]; *(shortx4*)(vd + 4)  = v0.v4[1];
            *(shortx4*)(vd + 8) = v1.v4[0]; *(shortx4*)(vd + 12) = v1.v4[1];
        }
        __syncthreads();
#pragma unroll
        for (int kl = 0; kl < 64; kl += 32) {
            union { bf16x8 v; ushort u[8]; } bfr, afr[4];
#pragma unroll
            for (int i = 0; i < 8; ++i) {
                int n = kl + fk + i;
                bfr.u[i] = kS[n * 68 + w * 16 + fr];
#pragma unroll
                for (int mt = 0; mt < 4; ++mt)
                    afr[mt].u[i] = vS[n * 68 + mt * 16 + fr];
            }
            union { bf16x8 v; ushort u[8]; } ones;
            ushort ov = (fr == 0) ? (ushort)0x3F80 : (ushort)0;  // A row 64 = 1.0
#pragma unroll
            for (int i = 0; i < 8; ++i) ones.u[i] = ov;
#pragma unroll
            for (int mt = 0; mt < 4; ++mt)
                acc[mt] = mfma_bf16(afr[mt].v, bfr.v, acc[mt]);
            acc[4] = mfma_bf16(ones.v, bfr.v, acc[4]);
        }
    }

    float* dst = kvp + ((size_t)bh * 8 + s) * (65 * 64);
#pragma unroll
    for (int mt = 0; mt < 4; ++mt)
#pragma unroll
        for (int r = 0; r < 4; ++r)
            dst[(mt * 16 + (lane >> 4) * 4 + r) * 64 + w * 16 + fr] = acc[mt][r];
    if (lane < 16) dst[64 * 64 + w * 16 + lane] = acc[4][0];
}

// reduce 8 partials, emit bf16 in k_num's layout: kvb [48][65][64]
__global__ void k_kvred(const float* __restrict__ kvp, ushort* __restrict__ kvb) {
    int t4 = (blockIdx.x * 256 + threadIdx.x) * 4;   // 195*256*4 == 199680 exactly
    int bh = t4 / 4160, rem = t4 % 4160;
    const float* p = kvp + (size_t)bh * 8 * 4160 + rem;
    float4 sum = {0.f, 0.f, 0.f, 0.f};
    for (int i = 0; i < 8; ++i) {
        float4 a = *(const float4*)(p + (size_t)i * 4160);
        sum.x += a.x; sum.y += a.y; sum.z += a.z; sum.w += a.w;
    }
    shortx4 o;
    o[0] = (short)f2b(sum.x); o[1] = (short)f2b(sum.y);
    o[2] = (short)f2b(sum.z); o[3] = (short)f2b(sum.w);
    *(shortx4*)(kvb + t4) = o;
}

// ---------------- num + z + normed (MFMA) ----------------
// grid (48 bh, 32 l-chunks of 128). C = Q[128x64] @ kvT(64 x 80),
// kvT rows = e (output col), row 64 = ksum -> C col 64 = denominator.
__global__ __launch_bounds__(256) void k_num(const ushort* __restrict__ QKV,
                                             const ushort* __restrict__ kvb,
                                             ushort* __restrict__ normed) {
    const int bh = blockIdx.x, l0 = blockIdx.y * 128;
    const int bb = bh / 12, head = bh % 12;
    __shared__ ushort qsh[128 * 72];
    __shared__ ushort kvT[80 * 72];
    __shared__ float dnm[128];
    const int t = threadIdx.x, w = t >> 6, lane = t & 63;

    {   // vector-copy kv summary (already bf16, already [e][d] with ksum row)
        const ushort* kvbb = kvb + (size_t)bh * 4160;
        int c8 = (t & 7) * 8;
        for (int r0 = (t >> 3); r0 < 65; r0 += 32)
            *(shortx8*)(kvT + r0 * 72 + c8) = *(const shortx8*)(kvbb + r0 * 64 + c8);
    }
    for (int idx = t; idx < 15 * 72; idx += 256) kvT[65 * 72 + idx] = 0;

    const ushort* qg = QKV + (size_t)(bb * 4096 + l0) * 2304 + head * 64;
    {
        int row = t >> 3, c8 = (t & 7) * 8;
#pragma unroll
        for (int i = 0; i < 4; ++i) {
            shortx8 v = *(const shortx8*)(qg + (size_t)(i * 32 + row) * 2304 + c8);
            *(shortx8*)(qsh + (i * 32 + row) * 72 + c8) = v;
        }
    }
    __syncthreads();

    const int fr = lane & 15, fk = (lane >> 4) * 8;
    floatx4 acc[2][5] = {};
#pragma unroll
    for (int kc = 0; kc < 2; ++kc) {
        bf16x8 a[2], b[5];
#pragma unroll
        for (int rt = 0; rt < 2; ++rt)
            a[rt] = *(const bf16x8*)(qsh + (w * 32 + rt * 16 + fr) * 72 + kc * 32 + fk);
#pragma unroll
        for (int nt = 0; nt < 5; ++nt)
            b[nt] = *(const bf16x8*)(kvT + (nt * 16 + fr) * 72 + kc * 32 + fk);
#pragma unroll
        for (int rt = 0; rt < 2; ++rt)
#pragma unroll
            for (int nt = 0; nt < 5; ++nt)
                acc[rt][nt] = mfma_bf16(a[rt], b[nt], acc[rt][nt]);
    }
    if (fr == 0) {
#pragma unroll
        for (int rt = 0; rt < 2; ++rt)
#pragma unroll
            for (int r = 0; r < 4; ++r)
                dnm[w * 32 + rt * 16 + (lane >> 4) * 4 + r] = acc[rt][4][r];
    }
    __syncthreads();
#pragma unroll
    for (int rt = 0; rt < 2; ++rt) {
#pragma unroll
        for (int r = 0; r < 4; ++r) {
            int ml = w * 32 + rt * 16 + (lane >> 4) * 4 + r;
            float z = 1.f / dnm[ml];
            size_t base = (size_t)(bb * 4096 + l0 + ml) * 768 + head * 64;
#pragma unroll
            for (int nt = 0; nt < 4; ++nt)
                normed[base + nt * 16 + fr] = f2b(acc[rt][nt][r] * z);
        }
    }
}

// ---------------- launch ----------------
extern "C" void kernel_launch(void* const* d_in, const int* in_sizes, int n_in,
                              void* d_out, int out_size, void* d_ws, size_t ws_size,
                              hipStream_t stream) {
    const float* x  = (const float*)d_in[0];
    const float* Wq = (const float*)d_in[1];
    const float* bq = (const float*)d_in[2];
    const float* Wk = (const float*)d_in[3];
    const float* bk = (const float*)d_in[4];
    const float* Wv = (const float*)d_in[5];
    const float* bv = (const float*)d_in[6];
    const float* Wo = (const float*)d_in[7];
    const float* bo = (const float*)d_in[8];

    char* ws = (char*)d_ws;
    ushort* Xb   = (ushort*)(ws);                 // 25,165,824 B (reused as `normed`)
    ushort* Wt   = (ushort*)(ws + 25165824);      //  3,538,944 B  [2304][768] bf16
    ushort* Wot  = (ushort*)(ws + 28704768);      //  1,179,648 B  [768][768] bf16
    float*  bqkv = (float*)(ws + 29884416);       //      9,216 B
    ushort* QKV  = (ushort*)(ws + 29893632);      // 75,497,472 B  [16384][2304] bf16
    float*  kvp  = (float*)(ws + 105391104);      //  6,389,760 B  [48][8][65][64] fp32
    ushort* kvb  = (ushort*)(ws + 111780864);     //    399,360 B  [48][65][64] bf16
    ushort* normed = Xb;

    k_cvt  <<<dim3(6144),        256, 0, stream>>>(x, Xb);
    k_packw<<<dim3(12, 12, 4),   256, 0, stream>>>(Wq, Wk, Wv, Wo, Wt, Wot);
    k_bias <<<dim3(9),           256, 0, stream>>>(bq, bk, bv, bqkv);
    k_gemm<0><<<dim3(128, 18),   256, 0, stream>>>(Xb, Wt, bqkv, (void*)QKV, 2304);
    k_kv   <<<dim3(48, 8),       256, 0, stream>>>(QKV, kvp);
    k_kvred<<<dim3(195),         256, 0, stream>>>(kvp, kvb);
    k_num  <<<dim3(48, 32),      256, 0, stream>>>(QKV, kvb, normed);
    k_gemm<1><<<dim3(128, 6),    256, 0, stream>>>(normed, Wot, bo, d_out, 768);
}

// Round 3
// 237.848 us; speedup vs baseline: 1.2251x; 1.0537x over previous
//
#include <hip/hip_runtime.h>
#include <cstdint>
#include <cstddef>

#define DEVI __device__ __forceinline__

typedef short    shortx8 __attribute__((ext_vector_type(8)));
typedef short    shortx4 __attribute__((ext_vector_type(4)));
typedef short    shortx2 __attribute__((ext_vector_type(2)));
typedef __bf16   bf16x8  __attribute__((ext_vector_type(8)));
typedef float    floatx4 __attribute__((ext_vector_type(4)));

DEVI unsigned short f2b(float f) {
    union { float f; unsigned u; } a; a.f = f;
    unsigned r = a.u + 0x7fffu + ((a.u >> 16) & 1u);
    return (unsigned short)(r >> 16);
}
DEVI float b2f(unsigned short u) {
    union { unsigned u; float f; } a; a.u = ((unsigned)u) << 16;
    return a.f;
}

DEVI floatx4 mfma_bf16(bf16x8 a, bf16x8 b, floatx4 c) {
    return __builtin_amdgcn_mfma_f32_16x16x32_bf16(a, b, c, 0, 0, 0);
}

DEVI void glds16(const ushort* g, ushort* l) {
    __builtin_amdgcn_global_load_lds(
        (const __attribute__((address_space(1))) void*)g,
        (__attribute__((address_space(3))) void*)l, 16, 0, 0);
}

// ---------------- fused prep: x->bf16, W transposes, bias pack ----------------
__global__ void k_prep(const float* __restrict__ x, ushort* __restrict__ xb,
                       const float* __restrict__ Wq, const float* __restrict__ Wk,
                       const float* __restrict__ Wv, const float* __restrict__ Wo,
                       ushort* __restrict__ Wt, ushort* __restrict__ Wot,
                       const float* __restrict__ bq, const float* __restrict__ bk,
                       const float* __restrict__ bv, float* __restrict__ bqkv) {
    __shared__ float tile[64][65];
    const int bid = blockIdx.x, t = threadIdx.x;
    if (bid < 6144) {                      // x -> bf16
        size_t i = ((size_t)bid * 256 + t) * 8;
        float4 v0 = *(const float4*)(x + i);
        float4 v1 = *(const float4*)(x + i + 4);
        shortx8 o;
        o[0] = (short)f2b(v0.x); o[1] = (short)f2b(v0.y);
        o[2] = (short)f2b(v0.z); o[3] = (short)f2b(v0.w);
        o[4] = (short)f2b(v1.x); o[5] = (short)f2b(v1.y);
        o[6] = (short)f2b(v1.z); o[7] = (short)f2b(v1.w);
        *(shortx8*)(xb + i) = o;
    } else if (bid < 6720) {               // W [in][out] fp32 -> [out][in] bf16
        int pid = bid - 6144;
        int zi = pid / 144, rem = pid % 144;
        const float* W = (zi == 0) ? Wq : (zi == 1) ? Wk : (zi == 2) ? Wv : Wo;
        const int i0 = (rem / 12) * 64, j0 = (rem % 12) * 64;
        const int c = t & 63, r4 = t >> 6;
        for (int rr = r4; rr < 64; rr += 4)
            tile[rr][c] = W[(size_t)(i0 + rr) * 768 + j0 + c];
        __syncthreads();
        ushort* dst = (zi < 3) ? (Wt + (size_t)(zi * 768) * 768) : Wot;
        for (int jj = r4; jj < 64; jj += 4)
            dst[(size_t)(j0 + jj) * 768 + i0 + c] = f2b(tile[c][jj]);
    } else {                               // bias pack
        int j = (bid - 6720) * 256 + t;
        if (j < 2304) {
            const float* src = (j < 768) ? bq : (j < 1536) ? bk : bv;
            bqkv[j] = src[j % 768];
        }
    }
}

// ---------------- main GEMM: BK=64, XOR chunk swizzle ----------------
// LDS logical As[row][k0..63]; element (r,k) at r*64 + ((k>>3)^(r&7))*8 + (k&7).
// Staging: glds16 #i covers rows +i*8..+i*8+8, lane -> (row=lane>>3, slot=lane&7),
// source column permuted per lane so coalescing (full 128B rows) is preserved.
template <int MODE>
__global__ __launch_bounds__(256, 2) void k_gemm(
    const ushort* __restrict__ A, const ushort* __restrict__ Bt,
    const float* __restrict__ bias, void* __restrict__ Cout, int Ncols) {
    constexpr int K = 768;
    __shared__ ushort As[128 * 64];
    __shared__ ushort Bs[128 * 64];
    const int m0 = blockIdx.x * 128;
    const int n0 = blockIdx.y * 128;
    const int tid = threadIdx.x;
    const int w = tid >> 6, lane = tid & 63;

    const int lr = lane >> 3;                    // row within 8-row slab
    const int lc = ((lane & 7) ^ lr) * 8;        // swizzled source chunk
    const ushort* ag[4]; const ushort* bg[4]; ushort* al[4]; ushort* bl[4];
#pragma unroll
    for (int i = 0; i < 4; ++i) {
        ag[i] = A  + (size_t)(m0 + w * 32 + i * 8 + lr) * K + lc;
        bg[i] = Bt + (size_t)(n0 + w * 32 + i * 8 + lr) * K + lc;
        al[i] = As + (w * 32 + i * 8) * 64;      // wave-uniform LDS bases
        bl[i] = Bs + (w * 32 + i * 8) * 64;
    }

    const int rBase = (w >> 1) * 64;
    const int nBase = (w & 1) * 64;
    const int fr = lane & 15;
    const int q4 = lane >> 4;

    floatx4 acc[4][4] = {};

    for (int k0 = 0; k0 < K; k0 += 64) {
#pragma unroll
        for (int i = 0; i < 4; ++i) glds16(ag[i] + k0, al[i]);
#pragma unroll
        for (int i = 0; i < 4; ++i) glds16(bg[i] + k0, bl[i]);
        __syncthreads();
#pragma unroll
        for (int kc = 0; kc < 2; ++kc) {
            const int off = ((kc * 4 + q4) ^ (fr & 7)) * 8;
            bf16x8 af[4], bf[4];
#pragma unroll
            for (int rt = 0; rt < 4; ++rt)
                af[rt] = *(const bf16x8*)(As + (rBase + rt * 16 + fr) * 64 + off);
#pragma unroll
            for (int nt = 0; nt < 4; ++nt)
                bf[nt] = *(const bf16x8*)(Bs + (nBase + nt * 16 + fr) * 64 + off);
#pragma unroll
            for (int rt = 0; rt < 4; ++rt)
#pragma unroll
                for (int nt = 0; nt < 4; ++nt)
                    acc[rt][nt] = mfma_bf16(af[rt], bf[nt], acc[rt][nt]);
        }
        __syncthreads();
    }

#pragma unroll
    for (int rt = 0; rt < 4; ++rt) {
#pragma unroll
        for (int nt = 0; nt < 4; ++nt) {
#pragma unroll
            for (int r = 0; r < 4; ++r) {
                int m = m0 + rBase + rt * 16 + q4 * 4 + r;
                int n = n0 + nBase + nt * 16 + fr;
                float v = acc[rt][nt][r] + bias[n];
                if (MODE == 0) {
                    if (n < 1536) v = (v > 0.f) ? (v + 1.f) : __expf(v);  // phi
                    ((ushort*)Cout)[(size_t)m * Ncols + n] = f2b(v);
                } else {
                    ((float*)Cout)[(size_t)m * Ncols + n] = v;
                }
            }
        }
    }
}

// ---------------- kv + ksum via MFMA (stride 70: conflict-free reads) ---------
__global__ __launch_bounds__(256) void k_kv(const ushort* __restrict__ QKV,
                                            float* __restrict__ kvp) {
    const int bh = blockIdx.x, s = blockIdx.y;
    const int bb = bh / 12, head = bh % 12;
    __shared__ ushort kS[64 * 70];
    __shared__ ushort vS[64 * 70];
    const int t = threadIdx.x, w = t >> 6, lane = t & 63;
    const int fr = lane & 15, fk = (lane >> 4) * 8;

    floatx4 acc[5] = {};
    const int n_ld = t >> 2, c16 = (t & 3) * 16;
    const ushort* base = QKV + (size_t)(bb * 4096 + s * 512) * 2304 + 768 + head * 64 + c16;

    for (int rr = 0; rr < 8; ++rr) {
        if (rr) __syncthreads();
        {
            const ushort* kp = base + (size_t)(rr * 64 + n_ld) * 2304;
            union { shortx8 v8; shortx2 v2[4]; } k0, k1, v0, v1;
            k0.v8 = *(const shortx8*)(kp);
            k1.v8 = *(const shortx8*)(kp + 8);
            v0.v8 = *(const shortx8*)(kp + 768);
            v1.v8 = *(const shortx8*)(kp + 776);
            ushort* kd = kS + n_ld * 70 + c16;
            ushort* vd = vS + n_ld * 70 + c16;
#pragma unroll
            for (int i = 0; i < 4; ++i) {
                *(shortx2*)(kd + 2 * i)     = k0.v2[i];
                *(shortx2*)(kd + 8 + 2 * i) = k1.v2[i];
                *(shortx2*)(vd + 2 * i)     = v0.v2[i];
                *(shortx2*)(vd + 8 + 2 * i) = v1.v2[i];
            }
        }
        __syncthreads();
#pragma unroll
        for (int kl = 0; kl < 64; kl += 32) {
            union { bf16x8 v; ushort u[8]; } bfr, afr[4];
#pragma unroll
            for (int i = 0; i < 8; ++i) {
                int n = kl + fk + i;
                bfr.u[i] = kS[n * 70 + w * 16 + fr];
#pragma unroll
                for (int mt = 0; mt < 4; ++mt)
                    afr[mt].u[i] = vS[n * 70 + mt * 16 + fr];
            }
            union { bf16x8 v; ushort u[8]; } ones;
            ushort ov = (fr == 0) ? (ushort)0x3F80 : (ushort)0;
#pragma unroll
            for (int i = 0; i < 8; ++i) ones.u[i] = ov;
#pragma unroll
            for (int mt = 0; mt < 4; ++mt)
                acc[mt] = mfma_bf16(afr[mt].v, bfr.v, acc[mt]);
            acc[4] = mfma_bf16(ones.v, bfr.v, acc[4]);
        }
    }

    float* dst = kvp + ((size_t)bh * 8 + s) * (65 * 64);
#pragma unroll
    for (int mt = 0; mt < 4; ++mt)
#pragma unroll
        for (int r = 0; r < 4; ++r)
            dst[(mt * 16 + (lane >> 4) * 4 + r) * 64 + w * 16 + fr] = acc[mt][r];
    if (lane < 16) dst[64 * 64 + w * 16 + lane] = acc[4][0];
}

// reduce 8 partials, emit bf16: kvb [48][65][64]
__global__ void k_kvred(const float* __restrict__ kvp, ushort* __restrict__ kvb) {
    int t4 = (blockIdx.x * 256 + threadIdx.x) * 4;   // 195*256*4 == 199680
    int bh = t4 / 4160, rem = t4 % 4160;
    const float* p = kvp + (size_t)bh * 8 * 4160 + rem;
    float4 sum = {0.f, 0.f, 0.f, 0.f};
    for (int i = 0; i < 8; ++i) {
        float4 a = *(const float4*)(p + (size_t)i * 4160);
        sum.x += a.x; sum.y += a.y; sum.z += a.z; sum.w += a.w;
    }
    shortx4 o;
    o[0] = (short)f2b(sum.x); o[1] = (short)f2b(sum.y);
    o[2] = (short)f2b(sum.z); o[3] = (short)f2b(sum.w);
    *(shortx4*)(kvb + t4) = o;
}

// ---------------- num + z + normed (MFMA) ----------------
__global__ __launch_bounds__(256) void k_num(const ushort* __restrict__ QKV,
                                             const ushort* __restrict__ kvb,
                                             ushort* __restrict__ normed) {
    const int bh = blockIdx.x, l0 = blockIdx.y * 128;
    const int bb = bh / 12, head = bh % 12;
    __shared__ ushort qsh[128 * 72];
    __shared__ ushort kvT[80 * 72];
    __shared__ float dnm[128];
    const int t = threadIdx.x, w = t >> 6, lane = t & 63;

    {
        const ushort* kvbb = kvb + (size_t)bh * 4160;
        int c8 = (t & 7) * 8;
        for (int r0 = (t >> 3); r0 < 65; r0 += 32)
            *(shortx8*)(kvT + r0 * 72 + c8) = *(const shortx8*)(kvbb + r0 * 64 + c8);
    }
    for (int idx = t; idx < 15 * 72; idx += 256) kvT[65 * 72 + idx] = 0;

    const ushort* qg = QKV + (size_t)(bb * 4096 + l0) * 2304 + head * 64;
    {
        int row = t >> 3, c8 = (t & 7) * 8;
#pragma unroll
        for (int i = 0; i < 4; ++i) {
            shortx8 v = *(const shortx8*)(qg + (size_t)(i * 32 + row) * 2304 + c8);
            *(shortx8*)(qsh + (i * 32 + row) * 72 + c8) = v;
        }
    }
    __syncthreads();

    const int fr = lane & 15, fk = (lane >> 4) * 8;
    floatx4 acc[2][5] = {};
#pragma unroll
    for (int kc = 0; kc < 2; ++kc) {
        bf16x8 a[2], b[5];
#pragma unroll
        for (int rt = 0; rt < 2; ++rt)
            a[rt] = *(const bf16x8*)(qsh + (w * 32 + rt * 16 + fr) * 72 + kc * 32 + fk);
#pragma unroll
        for (int nt = 0; nt < 5; ++nt)
            b[nt] = *(const bf16x8*)(kvT + (nt * 16 + fr) * 72 + kc * 32 + fk);
#pragma unroll
        for (int rt = 0; rt < 2; ++rt)
#pragma unroll
            for (int nt = 0; nt < 5; ++nt)
                acc[rt][nt] = mfma_bf16(a[rt], b[nt], acc[rt][nt]);
    }
    if (fr == 0) {
#pragma unroll
        for (int rt = 0; rt < 2; ++rt)
#pragma unroll
            for (int r = 0; r < 4; ++r)
                dnm[w * 32 + rt * 16 + (lane >> 4) * 4 + r] = acc[rt][4][r];
    }
    __syncthreads();
#pragma unroll
    for (int rt = 0; rt < 2; ++rt) {
#pragma unroll
        for (int r = 0; r < 4; ++r) {
            int ml = w * 32 + rt * 16 + (lane >> 4) * 4 + r;
            float z = 1.f / dnm[ml];
            size_t base = (size_t)(bb * 4096 + l0 + ml) * 768 + head * 64;
#pragma unroll
            for (int nt = 0; nt < 4; ++nt)
                normed[base + nt * 16 + fr] = f2b(acc[rt][nt][r] * z);
        }
    }
}

// ---------------- launch ----------------
extern "C" void kernel_launch(void* const* d_in, const int* in_sizes, int n_in,
                              void* d_out, int out_size, void* d_ws, size_t ws_size,
                              hipStream_t stream) {
    const float* x  = (const float*)d_in[0];
    const float* Wq = (const float*)d_in[1];
    const float* bq = (const float*)d_in[2];
    const float* Wk = (const float*)d_in[3];
    const float* bk = (const float*)d_in[4];
    const float* Wv = (const float*)d_in[5];
    const float* bv = (const float*)d_in[6];
    const float* Wo = (const float*)d_in[7];
    const float* bo = (const float*)d_in[8];

    char* ws = (char*)d_ws;
    ushort* Xb   = (ushort*)(ws);                 // 25,165,824 B (reused as normed)
    ushort* Wt   = (ushort*)(ws + 25165824);      //  3,538,944 B
    ushort* Wot  = (ushort*)(ws + 28704768);      //  1,179,648 B
    float*  bqkv = (float*)(ws + 29884416);       //      9,216 B
    ushort* QKV  = (ushort*)(ws + 29893632);      // 75,497,472 B
    float*  kvp  = (float*)(ws + 105391104);      //  6,389,760 B
    ushort* kvb  = (ushort*)(ws + 111780864);     //    399,360 B
    ushort* normed = Xb;

    k_prep <<<dim3(6729),      256, 0, stream>>>(x, Xb, Wq, Wk, Wv, Wo, Wt, Wot,
                                                 bq, bk, bv, bqkv);
    k_gemm<0><<<dim3(128, 18), 256, 0, stream>>>(Xb, Wt, bqkv, (void*)QKV, 2304);
    k_kv   <<<dim3(48, 8),     256, 0, stream>>>(QKV, kvp);
    k_kvred<<<dim3(195),       256, 0, stream>>>(kvp, kvb);
    k_num  <<<dim3(48, 32),    256, 0, stream>>>(QKV, kvb, normed);
    k_gemm<1><<<dim3(128, 6),  256, 0, stream>>>(normed, Wot, bo, d_out, 768);
}